// Round 1
// baseline (9251.505 us; speedup 1.0000x reference)
//
#include <hip/hip_runtime.h>

#define N_NODES 100000
#define D 256
#define NT 4

// ---------------- counting / bucketing ----------------

template<int SHAPE>
__global__ void k_count(const int* __restrict__ idx, const int* __restrict__ etype,
                        int E, int* __restrict__ counts, int* __restrict__ hist) {
    int e = blockIdx.x * 256 + threadIdx.x;
    if (e >= E) return;
    int t = etype[e];
    int dst = idx[(size_t)SHAPE * E + (size_t)SHAPE * e];  // row 1, first slot
    atomicAdd(&counts[t * N_NODES + dst], 1);
    atomicAdd(&hist[t], 1);
}

__global__ void k_offsets(const int* __restrict__ hist, int* __restrict__ offs,
                          int* __restrict__ cursor) {
    if (threadIdx.x == 0 && blockIdx.x == 0) {
        int acc = 0;
        for (int t = 0; t < NT; ++t) { offs[t] = acc; cursor[t] = acc; acc += hist[t]; }
    }
}

__global__ void k_bucket(const int* __restrict__ etype, int E,
                         int* __restrict__ cursor, int* __restrict__ bucket) {
    int e = blockIdx.x * 256 + threadIdx.x;
    if (e >= E) return;
    int t = etype[e];
    int pos = atomicAdd(&cursor[t], 1);
    bucket[pos] = e;
}

// ---------------- W transpose (once) ----------------

__global__ void k_transpose(const float* __restrict__ W, float* __restrict__ WT) {
    int k = blockIdx.x, j = threadIdx.x;
    WT[k * D + j] = W[j * D + k];
}

// ---------------- out = x @ W^T + b  (WT is [k][j]) ----------------

__global__ __launch_bounds__(256) void k_init_out(const float* __restrict__ x,
        const float* __restrict__ WT, const float* __restrict__ b,
        float* __restrict__ out, int n) {
    __shared__ float xs[64][32];
    __shared__ float at[32][256];
    int row0 = blockIdx.x * 64;
    int nR = min(64, n - row0);
    int tid = threadIdx.x;
    int c0 = (tid & 63) * 4;
    int r0 = (tid >> 6) * 16;
    float acc[16][4];
    #pragma unroll
    for (int r = 0; r < 16; ++r)
        for (int m = 0; m < 4; ++m) acc[r][m] = 0.f;

    for (int kk = 0; kk < D; kk += 32) {
        #pragma unroll
        for (int it = 0; it < 2; ++it) {
            int f = it * 256 + tid;
            int r = f >> 3, q = f & 7;
            int gr = row0 + (r < nR ? r : nR - 1);
            float4 v = *(const float4*)&x[(size_t)gr * D + kk + q * 4];
            *(float4*)&xs[r][q * 4] = v;
        }
        #pragma unroll
        for (int it = 0; it < 8; ++it) {
            int f = it * 256 + tid;
            int k = f >> 6, j4 = f & 63;
            float4 v = *(const float4*)&WT[(size_t)(kk + k) * D + j4 * 4];
            *(float4*)&at[k][j4 * 4] = v;
        }
        __syncthreads();
        #pragma unroll
        for (int k4 = 0; k4 < 8; ++k4) {
            float xv[16][4];
            #pragma unroll
            for (int r = 0; r < 16; ++r) {
                float4 v = *(const float4*)&xs[r0 + r][k4 * 4];
                xv[r][0] = v.x; xv[r][1] = v.y; xv[r][2] = v.z; xv[r][3] = v.w;
            }
            #pragma unroll
            for (int m = 0; m < 4; ++m) {
                float4 w = *(const float4*)&at[k4 * 4 + m][c0];
                #pragma unroll
                for (int r = 0; r < 16; ++r) {
                    acc[r][0] = fmaf(xv[r][m], w.x, acc[r][0]);
                    acc[r][1] = fmaf(xv[r][m], w.y, acc[r][1]);
                    acc[r][2] = fmaf(xv[r][m], w.z, acc[r][2]);
                    acc[r][3] = fmaf(xv[r][m], w.w, acc[r][3]);
                }
            }
        }
        __syncthreads();
    }
    float4 bv = *(const float4*)&b[c0];
    #pragma unroll
    for (int r = 0; r < 16; ++r) {
        int rr = r0 + r;
        if (rr < nR) {
            float4 o;
            o.x = acc[r][0] + bv.x; o.y = acc[r][1] + bv.y;
            o.z = acc[r][2] + bv.z; o.w = acc[r][3] + bv.w;
            *(float4*)&out[(size_t)(row0 + rr) * D + c0] = o;
        }
    }
}

// ---------------- per-type gather-GEMM + normalized scatter ----------------

template<int SHAPE>
__global__ __launch_bounds__(256) void k_edge(const float* __restrict__ x,
        const int* __restrict__ idx, const float* __restrict__ A,
        float* __restrict__ out, int E,
        const int* __restrict__ counts, const int* __restrict__ hist,
        const int* __restrict__ offs, const int* __restrict__ bucket) {
    constexpr int K = SHAPE * 256;
    __shared__ float xs[64][32];
    __shared__ float at[32][256];
    __shared__ int src0S[64], src1S[64], dstS[64];
    __shared__ float normS[64];

    int t = blockIdx.y;
    int cnt = hist[t];
    int tile = blockIdx.x * 64;
    if (tile >= cnt) return;
    int nE = min(64, cnt - tile);
    int base = offs[t] + tile;
    int tid = threadIdx.x;

    if (tid < 64) {
        bool valid = tid < nE;
        int e = valid ? bucket[base + tid] : 0;
        int dst = idx[(size_t)SHAPE * E + (size_t)SHAPE * e];
        dstS[tid] = dst;
        int c = counts[t * N_NODES + dst];
        normS[tid] = valid ? 1.0f / (float)(c > 1 ? c : 1) : 0.0f;
        src0S[tid] = valid ? idx[SHAPE * e] : 0;
        if (SHAPE == 2) src1S[tid] = valid ? idx[SHAPE * e + 1] : 0;
    }

    const float* At = A + (size_t)t * K * D;
    int c0 = (tid & 63) * 4;
    int r0 = (tid >> 6) * 16;
    float acc[16][4];
    #pragma unroll
    for (int r = 0; r < 16; ++r)
        for (int m = 0; m < 4; ++m) acc[r][m] = 0.f;

    __syncthreads();
    for (int kk = 0; kk < K; kk += 32) {
        #pragma unroll
        for (int it = 0; it < 2; ++it) {
            int f = it * 256 + tid;
            int r = f >> 3, q = f & 7;
            int node;
            if (SHAPE == 1) node = src0S[r];
            else            node = (kk < 256) ? src0S[r] : src1S[r];
            int col = (kk & 255) + q * 4;
            float4 v = *(const float4*)&x[(size_t)node * D + col];
            *(float4*)&xs[r][q * 4] = v;
        }
        #pragma unroll
        for (int it = 0; it < 8; ++it) {
            int f = it * 256 + tid;
            int k = f >> 6, j4 = f & 63;
            float4 v = *(const float4*)&At[(size_t)(kk + k) * D + j4 * 4];
            *(float4*)&at[k][j4 * 4] = v;
        }
        __syncthreads();
        #pragma unroll
        for (int k4 = 0; k4 < 8; ++k4) {
            float xv[16][4];
            #pragma unroll
            for (int r = 0; r < 16; ++r) {
                float4 v = *(const float4*)&xs[r0 + r][k4 * 4];
                xv[r][0] = v.x; xv[r][1] = v.y; xv[r][2] = v.z; xv[r][3] = v.w;
            }
            #pragma unroll
            for (int m = 0; m < 4; ++m) {
                float4 w = *(const float4*)&at[k4 * 4 + m][c0];
                #pragma unroll
                for (int r = 0; r < 16; ++r) {
                    acc[r][0] = fmaf(xv[r][m], w.x, acc[r][0]);
                    acc[r][1] = fmaf(xv[r][m], w.y, acc[r][1]);
                    acc[r][2] = fmaf(xv[r][m], w.z, acc[r][2]);
                    acc[r][3] = fmaf(xv[r][m], w.w, acc[r][3]);
                }
            }
        }
        __syncthreads();
    }
    // epilogue: normalized atomic scatter into out
    #pragma unroll
    for (int r = 0; r < 16; ++r) {
        int rr = r0 + r;
        if (rr < nE) {
            float nm = normS[rr];
            float* o = &out[(size_t)dstS[rr] * D + c0];
            atomicAdd(o + 0, nm * acc[r][0]);
            atomicAdd(o + 1, nm * acc[r][1]);
            atomicAdd(o + 2, nm * acc[r][2]);
            atomicAdd(o + 3, nm * acc[r][3]);
        }
    }
}

// ---------------- launch ----------------

extern "C" void kernel_launch(void* const* d_in, const int* in_sizes, int n_in,
                              void* d_out, int out_size, void* d_ws, size_t ws_size,
                              hipStream_t stream) {
    const float* x  = (const float*)d_in[0];
    const int* idx1 = (const int*)d_in[1];
    const int* ty1  = (const int*)d_in[2];
    const int* idx2 = (const int*)d_in[3];
    const int* ty2  = (const int*)d_in[4];
    const float* A1 = (const float*)d_in[5];
    const float* A2 = (const float*)d_in[6];
    const float* W  = (const float*)d_in[7];
    const float* b  = (const float*)d_in[8];
    float* out = (float*)d_out;

    int E1 = in_sizes[2];
    int E2 = in_sizes[4];
    int maxE = E1 > E2 ? E1 : E2;

    int* counts = (int*)d_ws;                 // NT*N ints
    int* hist   = counts + NT * N_NODES;      // 4
    int* offs   = hist + 4;                   // 4
    int* cursor = offs + 4;                   // 4
    int* bucket = cursor + 4;                 // maxE ints
    float* WT   = (float*)(bucket + maxE);    // D*D floats

    // dense part: out = x @ W^T + b
    k_transpose<<<D, D, 0, stream>>>(W, WT);
    k_init_out<<<(N_NODES + 63) / 64, 256, 0, stream>>>(x, WT, b, out, N_NODES);

    // ---- stage 1 (shape=1) ----
    hipMemsetAsync(counts, 0, (size_t)(NT * N_NODES + 4) * sizeof(int), stream);
    k_count<1><<<(E1 + 255) / 256, 256, 0, stream>>>(idx1, ty1, E1, counts, hist);
    k_offsets<<<1, 64, 0, stream>>>(hist, offs, cursor);
    k_bucket<<<(E1 + 255) / 256, 256, 0, stream>>>(ty1, E1, cursor, bucket);
    k_edge<1><<<dim3((E1 + 63) / 64, NT), 256, 0, stream>>>(
        x, idx1, A1, out, E1, counts, hist, offs, bucket);

    // ---- stage 2 (shape=2) ----
    hipMemsetAsync(counts, 0, (size_t)(NT * N_NODES + 4) * sizeof(int), stream);
    k_count<2><<<(E2 + 255) / 256, 256, 0, stream>>>(idx2, ty2, E2, counts, hist);
    k_offsets<<<1, 64, 0, stream>>>(hist, offs, cursor);
    k_bucket<<<(E2 + 255) / 256, 256, 0, stream>>>(ty2, E2, cursor, bucket);
    k_edge<2><<<dim3((E2 + 63) / 64, NT), 256, 0, stream>>>(
        x, idx2, A2, out, E2, counts, hist, offs, bucket);
}

// Round 2
// 3590.789 us; speedup vs baseline: 2.5765x; 2.5765x over previous
//
#include <hip/hip_runtime.h>

#define N_NODES 100000
#define D 256
#define NT 4

// ---------------- counting / bucketing ----------------

template<int SHAPE>
__global__ void k_count(const int* __restrict__ idx, const int* __restrict__ etype,
                        int E, int* __restrict__ counts, int* __restrict__ hist) {
    int e = blockIdx.x * 256 + threadIdx.x;
    bool valid = e < E;
    int t = valid ? etype[e] : -1;
    if (valid) {
        int dst = idx[(size_t)SHAPE * E + (size_t)SHAPE * e];  // row 1, first slot
        atomicAdd(&counts[t * N_NODES + dst], 1);
    }
    // wave-aggregated histogram: one atomic per wave per type
    int lane = threadIdx.x & 63;
    #pragma unroll
    for (int tt = 0; tt < NT; ++tt) {
        unsigned long long m = __ballot(t == tt);
        if (m && lane == (__ffsll((long long)m) - 1))
            atomicAdd(&hist[tt], __popcll(m));
    }
}

__global__ void k_offsets(const int* __restrict__ hist, int* __restrict__ offs,
                          int* __restrict__ cursor) {
    if (threadIdx.x == 0 && blockIdx.x == 0) {
        int acc = 0;
        for (int t = 0; t < NT; ++t) { offs[t] = acc; cursor[t] = acc; acc += hist[t]; }
    }
}

__global__ void k_bucket(const int* __restrict__ etype, int E,
                         int* __restrict__ cursor, int* __restrict__ bucket) {
    int e = blockIdx.x * 256 + threadIdx.x;
    bool valid = e < E;
    int t = valid ? etype[e] : -1;
    int lane = threadIdx.x & 63;
    #pragma unroll
    for (int tt = 0; tt < NT; ++tt) {
        unsigned long long m = __ballot(t == tt);
        if (!m) continue;
        int leader = __ffsll((long long)m) - 1;
        int base = 0;
        if (lane == leader) base = atomicAdd(&cursor[tt], __popcll(m));
        base = __shfl(base, leader);
        if (t == tt) {
            int rank = __popcll(m & ((1ull << lane) - 1ull));
            bucket[base + rank] = e;
        }
    }
}

// ---------------- W transpose (once) ----------------

__global__ void k_transpose(const float* __restrict__ W, float* __restrict__ WT) {
    int k = blockIdx.x, j = threadIdx.x;
    WT[k * D + j] = W[j * D + k];
}

// ---------------- out = x @ W^T + b  (WT is [k][j]) ----------------

__global__ __launch_bounds__(256) void k_init_out(const float* __restrict__ x,
        const float* __restrict__ WT, const float* __restrict__ b,
        float* __restrict__ out, int n) {
    __shared__ float xs[64][32];
    __shared__ float at[32][256];
    int row0 = blockIdx.x * 64;
    int nR = min(64, n - row0);
    int tid = threadIdx.x;
    int c0 = (tid & 63) * 4;
    int r0 = (tid >> 6) * 16;
    float acc[16][4];
    #pragma unroll
    for (int r = 0; r < 16; ++r)
        for (int m = 0; m < 4; ++m) acc[r][m] = 0.f;

    for (int kk = 0; kk < D; kk += 32) {
        #pragma unroll
        for (int it = 0; it < 2; ++it) {
            int f = it * 256 + tid;
            int r = f >> 3, q = f & 7;
            int gr = row0 + (r < nR ? r : nR - 1);
            float4 v = *(const float4*)&x[(size_t)gr * D + kk + q * 4];
            *(float4*)&xs[r][q * 4] = v;
        }
        #pragma unroll
        for (int it = 0; it < 8; ++it) {
            int f = it * 256 + tid;
            int k = f >> 6, j4 = f & 63;
            float4 v = *(const float4*)&WT[(size_t)(kk + k) * D + j4 * 4];
            *(float4*)&at[k][j4 * 4] = v;
        }
        __syncthreads();
        #pragma unroll
        for (int k4 = 0; k4 < 8; ++k4) {
            float xv[16][4];
            #pragma unroll
            for (int r = 0; r < 16; ++r) {
                float4 v = *(const float4*)&xs[r0 + r][k4 * 4];
                xv[r][0] = v.x; xv[r][1] = v.y; xv[r][2] = v.z; xv[r][3] = v.w;
            }
            #pragma unroll
            for (int m = 0; m < 4; ++m) {
                float4 w = *(const float4*)&at[k4 * 4 + m][c0];
                #pragma unroll
                for (int r = 0; r < 16; ++r) {
                    acc[r][0] = fmaf(xv[r][m], w.x, acc[r][0]);
                    acc[r][1] = fmaf(xv[r][m], w.y, acc[r][1]);
                    acc[r][2] = fmaf(xv[r][m], w.z, acc[r][2]);
                    acc[r][3] = fmaf(xv[r][m], w.w, acc[r][3]);
                }
            }
        }
        __syncthreads();
    }
    float4 bv = *(const float4*)&b[c0];
    #pragma unroll
    for (int r = 0; r < 16; ++r) {
        int rr = r0 + r;
        if (rr < nR) {
            float4 o;
            o.x = acc[r][0] + bv.x; o.y = acc[r][1] + bv.y;
            o.z = acc[r][2] + bv.z; o.w = acc[r][3] + bv.w;
            *(float4*)&out[(size_t)(row0 + rr) * D + c0] = o;
        }
    }
}

// ---------------- per-type gather-GEMM + normalized scatter ----------------

template<int SHAPE>
__global__ __launch_bounds__(256) void k_edge(const float* __restrict__ x,
        const int* __restrict__ idx, const float* __restrict__ A,
        float* __restrict__ out, int E,
        const int* __restrict__ counts, const int* __restrict__ hist,
        const int* __restrict__ offs, const int* __restrict__ bucket) {
    constexpr int K = SHAPE * 256;
    __shared__ float xs[64][32];
    __shared__ float at[32][256];
    __shared__ int src0S[64], src1S[64], dstS[64];
    __shared__ float normS[64];

    int t = blockIdx.y;
    int cnt = hist[t];
    int tile = blockIdx.x * 64;
    if (tile >= cnt) return;
    int nE = min(64, cnt - tile);
    int base = offs[t] + tile;
    int tid = threadIdx.x;

    if (tid < 64) {
        bool valid = tid < nE;
        int e = valid ? bucket[base + tid] : 0;
        int dst = idx[(size_t)SHAPE * E + (size_t)SHAPE * e];
        dstS[tid] = dst;
        int c = counts[t * N_NODES + dst];
        normS[tid] = valid ? 1.0f / (float)(c > 1 ? c : 1) : 0.0f;
        src0S[tid] = valid ? idx[SHAPE * e] : 0;
        if (SHAPE == 2) src1S[tid] = valid ? idx[SHAPE * e + 1] : 0;
    }

    const float* At = A + (size_t)t * K * D;
    int c0 = (tid & 63) * 4;
    int r0 = (tid >> 6) * 16;
    float acc[16][4];
    #pragma unroll
    for (int r = 0; r < 16; ++r)
        for (int m = 0; m < 4; ++m) acc[r][m] = 0.f;

    __syncthreads();
    for (int kk = 0; kk < K; kk += 32) {
        #pragma unroll
        for (int it = 0; it < 2; ++it) {
            int f = it * 256 + tid;
            int r = f >> 3, q = f & 7;
            int node;
            if (SHAPE == 1) node = src0S[r];
            else            node = (kk < 256) ? src0S[r] : src1S[r];
            int col = (kk & 255) + q * 4;
            float4 v = *(const float4*)&x[(size_t)node * D + col];
            *(float4*)&xs[r][q * 4] = v;
        }
        #pragma unroll
        for (int it = 0; it < 8; ++it) {
            int f = it * 256 + tid;
            int k = f >> 6, j4 = f & 63;
            float4 v = *(const float4*)&At[(size_t)(kk + k) * D + j4 * 4];
            *(float4*)&at[k][j4 * 4] = v;
        }
        __syncthreads();
        #pragma unroll
        for (int k4 = 0; k4 < 8; ++k4) {
            float xv[16][4];
            #pragma unroll
            for (int r = 0; r < 16; ++r) {
                float4 v = *(const float4*)&xs[r0 + r][k4 * 4];
                xv[r][0] = v.x; xv[r][1] = v.y; xv[r][2] = v.z; xv[r][3] = v.w;
            }
            #pragma unroll
            for (int m = 0; m < 4; ++m) {
                float4 w = *(const float4*)&at[k4 * 4 + m][c0];
                #pragma unroll
                for (int r = 0; r < 16; ++r) {
                    acc[r][0] = fmaf(xv[r][m], w.x, acc[r][0]);
                    acc[r][1] = fmaf(xv[r][m], w.y, acc[r][1]);
                    acc[r][2] = fmaf(xv[r][m], w.z, acc[r][2]);
                    acc[r][3] = fmaf(xv[r][m], w.w, acc[r][3]);
                }
            }
        }
        __syncthreads();
    }
    // epilogue: normalized atomic scatter into out
    #pragma unroll
    for (int r = 0; r < 16; ++r) {
        int rr = r0 + r;
        if (rr < nE) {
            float nm = normS[rr];
            float* o = &out[(size_t)dstS[rr] * D + c0];
            atomicAdd(o + 0, nm * acc[r][0]);
            atomicAdd(o + 1, nm * acc[r][1]);
            atomicAdd(o + 2, nm * acc[r][2]);
            atomicAdd(o + 3, nm * acc[r][3]);
        }
    }
}

// ---------------- launch ----------------

extern "C" void kernel_launch(void* const* d_in, const int* in_sizes, int n_in,
                              void* d_out, int out_size, void* d_ws, size_t ws_size,
                              hipStream_t stream) {
    const float* x  = (const float*)d_in[0];
    const int* idx1 = (const int*)d_in[1];
    const int* ty1  = (const int*)d_in[2];
    const int* idx2 = (const int*)d_in[3];
    const int* ty2  = (const int*)d_in[4];
    const float* A1 = (const float*)d_in[5];
    const float* A2 = (const float*)d_in[6];
    const float* W  = (const float*)d_in[7];
    const float* b  = (const float*)d_in[8];
    float* out = (float*)d_out;

    int E1 = in_sizes[2];
    int E2 = in_sizes[4];
    int maxE = E1 > E2 ? E1 : E2;

    int* counts = (int*)d_ws;                 // NT*N ints
    int* hist   = counts + NT * N_NODES;      // 4
    int* offs   = hist + 4;                   // 4
    int* cursor = offs + 4;                   // 4
    int* bucket = cursor + 4;                 // maxE ints
    float* WT   = (float*)(bucket + maxE);    // D*D floats

    // dense part: out = x @ W^T + b
    k_transpose<<<D, D, 0, stream>>>(W, WT);
    k_init_out<<<(N_NODES + 63) / 64, 256, 0, stream>>>(x, WT, b, out, N_NODES);

    // ---- stage 1 (shape=1) ----
    hipMemsetAsync(counts, 0, (size_t)(NT * N_NODES + 4) * sizeof(int), stream);
    k_count<1><<<(E1 + 255) / 256, 256, 0, stream>>>(idx1, ty1, E1, counts, hist);
    k_offsets<<<1, 64, 0, stream>>>(hist, offs, cursor);
    k_bucket<<<(E1 + 255) / 256, 256, 0, stream>>>(ty1, E1, cursor, bucket);
    k_edge<1><<<dim3((E1 + 63) / 64, NT), 256, 0, stream>>>(
        x, idx1, A1, out, E1, counts, hist, offs, bucket);

    // ---- stage 2 (shape=2) ----
    hipMemsetAsync(counts, 0, (size_t)(NT * N_NODES + 4) * sizeof(int), stream);
    k_count<2><<<(E2 + 255) / 256, 256, 0, stream>>>(idx2, ty2, E2, counts, hist);
    k_offsets<<<1, 64, 0, stream>>>(hist, offs, cursor);
    k_bucket<<<(E2 + 255) / 256, 256, 0, stream>>>(ty2, E2, cursor, bucket);
    k_edge<2><<<dim3((E2 + 63) / 64, NT), 256, 0, stream>>>(
        x, idx2, A2, out, E2, counts, hist, offs, bucket);
}

// Round 3
// 1498.786 us; speedup vs baseline: 6.1727x; 2.3958x over previous
//
#include <hip/hip_runtime.h>
#include <stdint.h>

#define N_NODES 100000
#define D 256
#define NT 4

typedef float f32x4 __attribute__((ext_vector_type(4)));
typedef __bf16 bf16x8 __attribute__((ext_vector_type(8)));

__device__ __forceinline__ unsigned short f2bf(float f) {
    unsigned u = __float_as_uint(f);
    u += 0x7FFF + ((u >> 16) & 1);        // round-to-nearest-even
    return (unsigned short)(u >> 16);
}

__device__ __forceinline__ void gload_lds16(const void* g, void* lds) {
    __builtin_amdgcn_global_load_lds(
        (const __attribute__((address_space(1))) unsigned int*)g,
        (__attribute__((address_space(3))) unsigned int*)lds, 16, 0, 0);
}

// ---------------- counting / bucketing (round-2, wave-aggregated) ----------------

template<int SHAPE>
__global__ void k_count(const int* __restrict__ idx, const int* __restrict__ etype,
                        int E, int* __restrict__ counts, int* __restrict__ hist) {
    int e = blockIdx.x * 256 + threadIdx.x;
    bool valid = e < E;
    int t = valid ? etype[e] : -1;
    if (valid) {
        int dst = idx[(size_t)SHAPE * E + (size_t)SHAPE * e];
        atomicAdd(&counts[t * N_NODES + dst], 1);
    }
    int lane = threadIdx.x & 63;
    #pragma unroll
    for (int tt = 0; tt < NT; ++tt) {
        unsigned long long m = __ballot(t == tt);
        if (m && lane == (__ffsll((long long)m) - 1))
            atomicAdd(&hist[tt], __popcll(m));
    }
}

__global__ void k_offsets(const int* __restrict__ hist, int* __restrict__ offs,
                          int* __restrict__ cursor) {
    if (threadIdx.x == 0 && blockIdx.x == 0) {
        int acc = 0;
        for (int t = 0; t < NT; ++t) { offs[t] = acc; cursor[t] = acc; acc += hist[t]; }
    }
}

__global__ void k_bucket(const int* __restrict__ etype, int E,
                         int* __restrict__ cursor, int* __restrict__ bucket) {
    int e = blockIdx.x * 256 + threadIdx.x;
    bool valid = e < E;
    int t = valid ? etype[e] : -1;
    int lane = threadIdx.x & 63;
    #pragma unroll
    for (int tt = 0; tt < NT; ++tt) {
        unsigned long long m = __ballot(t == tt);
        if (!m) continue;
        int leader = __ffsll((long long)m) - 1;
        int base = 0;
        if (lane == leader) base = atomicAdd(&cursor[tt], __popcll(m));
        base = __shfl(base, leader);
        if (t == tt) {
            int rank = __popcll(m & ((1ull << lane) - 1ull));
            bucket[base + rank] = e;
        }
    }
}

// ---------------- f32 -> bf16 elementwise convert (x and W) ----------------

__global__ __launch_bounds__(256) void k_cvt(const float* __restrict__ in,
        unsigned short* __restrict__ ob, int n8) {
    int i = blockIdx.x * 256 + threadIdx.x;
    if (i >= n8) return;
    const float4* p = (const float4*)in + (size_t)i * 2;
    float4 v0 = p[0], v1 = p[1];
    union { unsigned short us[8]; uint4 u4; } o;
    o.us[0] = f2bf(v0.x); o.us[1] = f2bf(v0.y); o.us[2] = f2bf(v0.z); o.us[3] = f2bf(v0.w);
    o.us[4] = f2bf(v1.x); o.us[5] = f2bf(v1.y); o.us[6] = f2bf(v1.z); o.us[7] = f2bf(v1.w);
    *(uint4*)(ob + (size_t)i * 8) = o.u4;
}

// ---------------- A[t][K][D] -> AT[t][D][K] bf16 (transpose + convert) ----------------

__global__ void k_cvt_At(const float* __restrict__ A, unsigned short* __restrict__ AT, int K) {
    __shared__ float tl[32][33];
    const float* Ab = A + (size_t)blockIdx.z * K * D;
    unsigned short* Ob = AT + (size_t)blockIdx.z * D * K;
    int k0 = blockIdx.x * 32, j0 = blockIdx.y * 32;
    int lx = threadIdx.x, ly = threadIdx.y;   // 32 x 8
    for (int yy = ly; yy < 32; yy += 8)
        tl[yy][lx] = Ab[(size_t)(k0 + yy) * D + j0 + lx];
    __syncthreads();
    for (int yy = ly; yy < 32; yy += 8)
        Ob[(size_t)(j0 + yy) * K + k0 + lx] = f2bf(tl[lx][yy]);
}

// ---------------- dense: out = x @ W^T + b  (MFMA bf16) ----------------
// Block: 64 rows x 256 cols, 4 waves (wave w -> cols w*64..w*64+63).
// xs: [64 rows][64 k] bf16, XOR-swizzled: chunk(r,q) at byte r*128 + (q^(r&7))*16.
// global_load_lds writes LINEAR (base+lane*16) -> pre-swizzle the SOURCE chunk.

__global__ __launch_bounds__(256) void k_init_mfma(const unsigned short* __restrict__ xb,
        const unsigned short* __restrict__ Wb, const float* __restrict__ bias,
        float* __restrict__ out, int n) {
    __shared__ __align__(16) char xs[64 * 128];
    int row0 = blockIdx.x * 64;
    int tid = threadIdx.x;
    int lane = tid & 63, w = tid >> 6;
    int l15 = lane & 15, l4 = lane >> 4;
    f32x4 acc[4][4];
    #pragma unroll
    for (int m = 0; m < 4; ++m)
        #pragma unroll
        for (int nn = 0; nn < 4; ++nn) acc[m][nn] = (f32x4)0.f;

    for (int kk = 0; kk < D; kk += 64) {
        #pragma unroll
        for (int it = 0; it < 2; ++it) {
            int f = it * 256 + tid;
            int r = f >> 3, q0 = f & 7;
            int q = q0 ^ (r & 7);
            int gr = row0 + r; if (gr >= n) gr = n - 1;
            gload_lds16(xb + (size_t)gr * D + kk + q * 8, xs + f * 16);
        }
        bf16x8 bfr[2][4];
        #pragma unroll
        for (int ks = 0; ks < 2; ++ks)
            #pragma unroll
            for (int nn = 0; nn < 4; ++nn) {
                int j = w * 64 + nn * 16 + l15;
                int k = kk + ks * 32 + l4 * 8;
                bfr[ks][nn] = *(const bf16x8*)(Wb + (size_t)j * D + k);
            }
        __syncthreads();   // drains vmcnt(0): gload_lds + bfr complete
        #pragma unroll
        for (int ks = 0; ks < 2; ++ks)
            #pragma unroll
            for (int m = 0; m < 4; ++m) {
                int R = m * 16 + l15;
                int C = ks * 4 + l4;
                bf16x8 a = *(const bf16x8*)(xs + R * 128 + ((C ^ (R & 7)) << 4));
                #pragma unroll
                for (int nn = 0; nn < 4; ++nn)
                    acc[m][nn] = __builtin_amdgcn_mfma_f32_16x16x32_bf16(
                        a, bfr[ks][nn], acc[m][nn], 0, 0, 0);
            }
        __syncthreads();
    }
    #pragma unroll
    for (int m = 0; m < 4; ++m)
        #pragma unroll
        for (int nn = 0; nn < 4; ++nn) {
            int col = w * 64 + nn * 16 + l15;
            float bv = bias[col];
            #pragma unroll
            for (int r = 0; r < 4; ++r) {
                int row = row0 + m * 16 + l4 * 4 + r;
                if (row < n) out[(size_t)row * D + col] = acc[m][nn][r] + bv;
            }
        }
}

// ---------------- per-type gather-GEMM (MFMA) + normalized atomic scatter ----------------

template<int SHAPE>
__global__ __launch_bounds__(256) void k_edge_mfma(const unsigned short* __restrict__ xb,
        const int* __restrict__ idx, const unsigned short* __restrict__ AT,
        float* __restrict__ out, int E,
        const int* __restrict__ counts, const int* __restrict__ hist,
        const int* __restrict__ offs, const int* __restrict__ bucket) {
    constexpr int K = SHAPE * 256;
    __shared__ __align__(16) char xs[64 * 128];
    __shared__ int srcS[SHAPE][64];
    __shared__ int dstS[64];
    __shared__ float normS[64];

    int t = blockIdx.y;
    int cnt = hist[t];
    int tile = blockIdx.x * 64;
    if (tile >= cnt) return;
    int nE = min(64, cnt - tile);
    int base = offs[t] + tile;
    int tid = threadIdx.x;

    if (tid < 64) {
        bool valid = tid < nE;
        int e = bucket[base + (valid ? tid : 0)];
        int dst = idx[(size_t)SHAPE * E + (size_t)SHAPE * e];
        dstS[tid] = dst;
        int c = counts[t * N_NODES + dst];
        normS[tid] = valid ? 1.0f / (float)(c > 1 ? c : 1) : 0.0f;
        srcS[0][tid] = idx[SHAPE * e];
        if (SHAPE == 2) srcS[SHAPE - 1][tid] = idx[SHAPE * e + SHAPE - 1];
    }
    __syncthreads();

    const unsigned short* Bt = AT + (size_t)t * D * K;
    int lane = tid & 63, w = tid >> 6;
    int l15 = lane & 15, l4 = lane >> 4;
    f32x4 acc[4][4];
    #pragma unroll
    for (int m = 0; m < 4; ++m)
        #pragma unroll
        for (int nn = 0; nn < 4; ++nn) acc[m][nn] = (f32x4)0.f;

    for (int kk = 0; kk < K; kk += 64) {
        #pragma unroll
        for (int it = 0; it < 2; ++it) {
            int f = it * 256 + tid;
            int r = f >> 3, q0 = f & 7;
            int q = q0 ^ (r & 7);
            int node = srcS[SHAPE == 2 ? (kk >> 8) : 0][r];
            int col = (kk & 255) + q * 8;
            gload_lds16(xb + (size_t)node * D + col, xs + f * 16);
        }
        bf16x8 bfr[2][4];
        #pragma unroll
        for (int ks = 0; ks < 2; ++ks)
            #pragma unroll
            for (int nn = 0; nn < 4; ++nn) {
                int j = w * 64 + nn * 16 + l15;
                int k = kk + ks * 32 + l4 * 8;
                bfr[ks][nn] = *(const bf16x8*)(Bt + (size_t)j * K + k);
            }
        __syncthreads();
        #pragma unroll
        for (int ks = 0; ks < 2; ++ks)
            #pragma unroll
            for (int m = 0; m < 4; ++m) {
                int R = m * 16 + l15;
                int C = ks * 4 + l4;
                bf16x8 a = *(const bf16x8*)(xs + R * 128 + ((C ^ (R & 7)) << 4));
                #pragma unroll
                for (int nn = 0; nn < 4; ++nn)
                    acc[m][nn] = __builtin_amdgcn_mfma_f32_16x16x32_bf16(
                        a, bfr[ks][nn], acc[m][nn], 0, 0, 0);
            }
        __syncthreads();
    }
    // epilogue: normalized atomic scatter
    #pragma unroll
    for (int m = 0; m < 4; ++m)
        #pragma unroll
        for (int r = 0; r < 4; ++r) {
            int rr = m * 16 + l4 * 4 + r;
            if (rr < nE) {
                float nm = normS[rr];
                size_t ob = (size_t)dstS[rr] * D;
                #pragma unroll
                for (int nn = 0; nn < 4; ++nn) {
                    int col = w * 64 + nn * 16 + l15;
                    atomicAdd(&out[ob + col], nm * acc[m][nn][r]);
                }
            }
        }
}

// ---------------- launch ----------------

extern "C" void kernel_launch(void* const* d_in, const int* in_sizes, int n_in,
                              void* d_out, int out_size, void* d_ws, size_t ws_size,
                              hipStream_t stream) {
    const float* x  = (const float*)d_in[0];
    const int* idx1 = (const int*)d_in[1];
    const int* ty1  = (const int*)d_in[2];
    const int* idx2 = (const int*)d_in[3];
    const int* ty2  = (const int*)d_in[4];
    const float* A1 = (const float*)d_in[5];
    const float* A2 = (const float*)d_in[6];
    const float* W  = (const float*)d_in[7];
    const float* b  = (const float*)d_in[8];
    float* out = (float*)d_out;

    int E1 = in_sizes[2];
    int E2 = in_sizes[4];
    int maxE = E1 > E2 ? E1 : E2;

    char* p = (char*)d_ws;
    unsigned short* xb  = (unsigned short*)p; p += (size_t)N_NODES * D * 2;   // 51.2 MB
    unsigned short* Wb  = (unsigned short*)p; p += (size_t)D * D * 2;         // 128 KB
    unsigned short* A1T = (unsigned short*)p; p += (size_t)NT * D * 256 * 2;  // 512 KB
    unsigned short* A2T = (unsigned short*)p; p += (size_t)NT * D * 512 * 2;  // 1 MB
    int* counts = (int*)p; p += (size_t)NT * N_NODES * 4;                     // 1.6 MB
    int* hist   = (int*)p; p += 16 * 4;   // hist[4], offs[4], cursor[4], pad
    int* offs   = hist + 4;
    int* cursor = hist + 8;
    int* bucket = (int*)p; p += (size_t)maxE * 4;

    // ---- prep: bf16 conversions / transposes ----
    k_cvt<<<(N_NODES * D / 8 + 255) / 256, 256, 0, stream>>>(x, xb, N_NODES * D / 8);
    k_cvt<<<(D * D / 8 + 255) / 256, 256, 0, stream>>>(W, Wb, D * D / 8);
    k_cvt_At<<<dim3(256 / 32, D / 32, NT), dim3(32, 8), 0, stream>>>(A1, A1T, 256);
    k_cvt_At<<<dim3(512 / 32, D / 32, NT), dim3(32, 8), 0, stream>>>(A2, A2T, 512);

    // ---- dense part ----
    k_init_mfma<<<(N_NODES + 63) / 64, 256, 0, stream>>>(xb, Wb, b, out, N_NODES);

    // ---- stage 1 (shape=1) ----
    hipMemsetAsync(counts, 0, (size_t)(NT * N_NODES + 4) * sizeof(int), stream);
    k_count<1><<<(E1 + 255) / 256, 256, 0, stream>>>(idx1, ty1, E1, counts, hist);
    k_offsets<<<1, 64, 0, stream>>>(hist, offs, cursor);
    k_bucket<<<(E1 + 255) / 256, 256, 0, stream>>>(ty1, E1, cursor, bucket);
    k_edge_mfma<1><<<dim3((E1 + 63) / 64, NT), 256, 0, stream>>>(
        xb, idx1, A1T, out, E1, counts, hist, offs, bucket);

    // ---- stage 2 (shape=2) ----
    hipMemsetAsync(counts, 0, (size_t)(NT * N_NODES + 4) * sizeof(int), stream);
    k_count<2><<<(E2 + 255) / 256, 256, 0, stream>>>(idx2, ty2, E2, counts, hist);
    k_offsets<<<1, 64, 0, stream>>>(hist, offs, cursor);
    k_bucket<<<(E2 + 255) / 256, 256, 0, stream>>>(ty2, E2, cursor, bucket);
    k_edge_mfma<2><<<dim3((E2 + 63) / 64, NT), 256, 0, stream>>>(
        xb, idx2, A2T, out, E2, counts, hist, offs, bucket);
}

// Round 4
// 696.605 us; speedup vs baseline: 13.2808x; 2.1516x over previous
//
#include <hip/hip_runtime.h>
#include <stdint.h>

#define N_NODES 100000
#define D 256
#define NT 4

typedef float f32x4 __attribute__((ext_vector_type(4)));
typedef __bf16 bf16x8 __attribute__((ext_vector_type(8)));

__device__ __forceinline__ unsigned short f2bf(float f) {
    unsigned u = __float_as_uint(f);
    u += 0x7FFF + ((u >> 16) & 1);        // round-to-nearest-even
    return (unsigned short)(u >> 16);
}

__device__ __forceinline__ void gload_lds16(const void* g, void* lds) {
    __builtin_amdgcn_global_load_lds(
        (const __attribute__((address_space(1))) unsigned int*)g,
        (__attribute__((address_space(3))) unsigned int*)lds, 16, 0, 0);
}

// ---------------- per-(type,dst) counting ----------------

template<int SHAPE>
__global__ void k_count(const int* __restrict__ idx, const int* __restrict__ etype,
                        int E, int* __restrict__ counts) {
    int e = blockIdx.x * 256 + threadIdx.x;
    if (e >= E) return;
    int t = etype[e];
    int dst = idx[(size_t)SHAPE * E + (size_t)SHAPE * e];
    atomicAdd(&counts[t * N_NODES + dst], 1);
}

// ---------------- exclusive scan over NT*N_NODES cells (3 kernels) ----------------

__global__ __launch_bounds__(256) void k_scan1(const int* __restrict__ in, int n,
        int* __restrict__ outv, int* __restrict__ bsums) {
    __shared__ int s[256];
    int tid = threadIdx.x;
    int i = blockIdx.x * 1024 + tid * 4;
    int v0 = 0, v1 = 0, v2 = 0, v3 = 0;
    if (i + 3 < n) {
        int4 v = *(const int4*)(in + i);
        v0 = v.x; v1 = v.y; v2 = v.z; v3 = v.w;
    } else {
        if (i     < n) v0 = in[i];
        if (i + 1 < n) v1 = in[i + 1];
        if (i + 2 < n) v2 = in[i + 2];
        if (i + 3 < n) v3 = in[i + 3];
    }
    int tsum = v0 + v1 + v2 + v3;
    s[tid] = tsum; __syncthreads();
    for (int off = 1; off < 256; off <<= 1) {
        int t = (tid >= off) ? s[tid - off] : 0;
        __syncthreads();
        s[tid] += t;
        __syncthreads();
    }
    int excl = s[tid] - tsum;
    if (tid == 255) bsums[blockIdx.x] = s[255];
    int o0 = excl, o1 = o0 + v0, o2 = o1 + v1, o3 = o2 + v2;
    if (i + 3 < n) {
        *(int4*)(outv + i) = make_int4(o0, o1, o2, o3);
    } else {
        if (i     < n) outv[i]     = o0;
        if (i + 1 < n) outv[i + 1] = o1;
        if (i + 2 < n) outv[i + 2] = o2;
        if (i + 3 < n) outv[i + 3] = o3;
    }
}

__global__ void k_scan2(int* __restrict__ bsums, int nb) {
    __shared__ int s[512];
    int t = threadIdx.x;
    int v = (t < nb) ? bsums[t] : 0;
    s[t] = v; __syncthreads();
    for (int off = 1; off < 512; off <<= 1) {
        int u = (t >= off) ? s[t - off] : 0;
        __syncthreads();
        s[t] += u;
        __syncthreads();
    }
    if (t < nb) bsums[t] = s[t] - v;   // exclusive
}

__global__ __launch_bounds__(256) void k_scan3(int* __restrict__ cellofs,
        int* __restrict__ cellcur, const int* __restrict__ bsums, int n) {
    int i = blockIdx.x * 1024 + threadIdx.x * 4;
    int add = bsums[blockIdx.x];
    if (i + 3 < n) {
        int4 v = *(int4*)(cellofs + i);
        v.x += add; v.y += add; v.z += add; v.w += add;
        *(int4*)(cellofs + i) = v;
        *(int4*)(cellcur + i) = v;
    } else {
        for (int k = 0; k < 4; ++k)
            if (i + k < n) { int v = cellofs[i + k] + add; cellofs[i + k] = v; cellcur[i + k] = v; }
    }
}

// ---------------- (type,dst)-sorted placement ----------------

template<int SHAPE>
__global__ void k_place(const int* __restrict__ idx, const int* __restrict__ etype, int E,
                        int* __restrict__ cellcur, int* __restrict__ bucket) {
    int e = blockIdx.x * 256 + threadIdx.x;
    if (e >= E) return;
    int t = etype[e];
    int dst = idx[(size_t)SHAPE * E + (size_t)SHAPE * e];
    int pos = atomicAdd(&cellcur[t * N_NODES + dst], 1);
    bucket[pos] = e;
}

// ---------------- f32 -> bf16 elementwise convert (x and W) ----------------

__global__ __launch_bounds__(256) void k_cvt(const float* __restrict__ in,
        unsigned short* __restrict__ ob, int n8) {
    int i = blockIdx.x * 256 + threadIdx.x;
    if (i >= n8) return;
    const float4* p = (const float4*)in + (size_t)i * 2;
    float4 v0 = p[0], v1 = p[1];
    union { unsigned short us[8]; uint4 u4; } o;
    o.us[0] = f2bf(v0.x); o.us[1] = f2bf(v0.y); o.us[2] = f2bf(v0.z); o.us[3] = f2bf(v0.w);
    o.us[4] = f2bf(v1.x); o.us[5] = f2bf(v1.y); o.us[6] = f2bf(v1.z); o.us[7] = f2bf(v1.w);
    *(uint4*)(ob + (size_t)i * 8) = o.u4;
}

// ---------------- A[t][K][D] -> AT[t][D][K] bf16 (transpose + convert) ----------------

__global__ void k_cvt_At(const float* __restrict__ A, unsigned short* __restrict__ AT, int K) {
    __shared__ float tl[32][33];
    const float* Ab = A + (size_t)blockIdx.z * K * D;
    unsigned short* Ob = AT + (size_t)blockIdx.z * D * K;
    int k0 = blockIdx.x * 32, j0 = blockIdx.y * 32;
    int lx = threadIdx.x, ly = threadIdx.y;   // 32 x 8
    for (int yy = ly; yy < 32; yy += 8)
        tl[yy][lx] = Ab[(size_t)(k0 + yy) * D + j0 + lx];
    __syncthreads();
    for (int yy = ly; yy < 32; yy += 8)
        Ob[(size_t)(j0 + yy) * K + k0 + lx] = f2bf(tl[lx][yy]);
}

// ---------------- dense: out = x @ W^T + b  (MFMA bf16) ----------------

__global__ __launch_bounds__(256) void k_init_mfma(const unsigned short* __restrict__ xb,
        const unsigned short* __restrict__ Wb, const float* __restrict__ bias,
        float* __restrict__ out, int n) {
    __shared__ __align__(16) char xs[64 * 128];
    int row0 = blockIdx.x * 64;
    int tid = threadIdx.x;
    int lane = tid & 63, w = tid >> 6;
    int l15 = lane & 15, l4 = lane >> 4;
    f32x4 acc[4][4];
    #pragma unroll
    for (int m = 0; m < 4; ++m)
        #pragma unroll
        for (int nn = 0; nn < 4; ++nn) acc[m][nn] = (f32x4)0.f;

    for (int kk = 0; kk < D; kk += 64) {
        #pragma unroll
        for (int it = 0; it < 2; ++it) {
            int f = it * 256 + tid;
            int r = f >> 3, q0 = f & 7;
            int q = q0 ^ (r & 7);
            int gr = row0 + r; if (gr >= n) gr = n - 1;
            gload_lds16(xb + (size_t)gr * D + kk + q * 8, xs + f * 16);
        }
        bf16x8 bfr[2][4];
        #pragma unroll
        for (int ks = 0; ks < 2; ++ks)
            #pragma unroll
            for (int nn = 0; nn < 4; ++nn) {
                int j = w * 64 + nn * 16 + l15;
                int k = kk + ks * 32 + l4 * 8;
                bfr[ks][nn] = *(const bf16x8*)(Wb + (size_t)j * D + k);
            }
        __syncthreads();
        #pragma unroll
        for (int ks = 0; ks < 2; ++ks)
            #pragma unroll
            for (int m = 0; m < 4; ++m) {
                int R = m * 16 + l15;
                int C = ks * 4 + l4;
                bf16x8 a = *(const bf16x8*)(xs + R * 128 + ((C ^ (R & 7)) << 4));
                #pragma unroll
                for (int nn = 0; nn < 4; ++nn)
                    acc[m][nn] = __builtin_amdgcn_mfma_f32_16x16x32_bf16(
                        a, bfr[ks][nn], acc[m][nn], 0, 0, 0);
            }
        __syncthreads();
    }
    #pragma unroll
    for (int m = 0; m < 4; ++m)
        #pragma unroll
        for (int nn = 0; nn < 4; ++nn) {
            int col = w * 64 + nn * 16 + l15;
            float bv = bias[col];
            #pragma unroll
            for (int r = 0; r < 4; ++r) {
                int row = row0 + m * 16 + l4 * 4 + r;
                if (row < n) out[(size_t)row * D + col] = acc[m][nn][r] + bv;
            }
        }
}

// ---------------- per-type gather-GEMM (MFMA) + normalized atomic scatter ----------------

template<int SHAPE>
__global__ __launch_bounds__(256) void k_edge_mfma(const unsigned short* __restrict__ xb,
        const int* __restrict__ idx, const unsigned short* __restrict__ AT,
        float* __restrict__ out, int E,
        const int* __restrict__ counts, const int* __restrict__ cellofs,
        const int* __restrict__ bucket) {
    constexpr int K = SHAPE * 256;
    __shared__ __align__(16) char xs[64 * 128];
    __shared__ int srcS[SHAPE][64];
    __shared__ int dstS[64];
    __shared__ float normS[64];

    int t = blockIdx.y;
    int offs_t = cellofs[t * N_NODES];
    int end_t = (t == NT - 1) ? E : cellofs[(t + 1) * N_NODES];
    int cnt = end_t - offs_t;
    int tile = blockIdx.x * 64;
    if (tile >= cnt) return;
    int nE = min(64, cnt - tile);
    int base = offs_t + tile;
    int tid = threadIdx.x;

    if (tid < 64) {
        bool valid = tid < nE;
        int e = bucket[base + (valid ? tid : 0)];
        int dst = idx[(size_t)SHAPE * E + (size_t)SHAPE * e];
        dstS[tid] = dst;
        int c = counts[t * N_NODES + dst];
        normS[tid] = valid ? 1.0f / (float)(c > 1 ? c : 1) : 0.0f;
        srcS[0][tid] = idx[SHAPE * e];
        if (SHAPE == 2) srcS[SHAPE - 1][tid] = idx[SHAPE * e + SHAPE - 1];
    }
    __syncthreads();

    const unsigned short* Bt = AT + (size_t)t * D * K;
    int lane = tid & 63, w = tid >> 6;
    int l15 = lane & 15, l4 = lane >> 4;
    f32x4 acc[4][4];
    #pragma unroll
    for (int m = 0; m < 4; ++m)
        #pragma unroll
        for (int nn = 0; nn < 4; ++nn) acc[m][nn] = (f32x4)0.f;

    for (int kk = 0; kk < K; kk += 64) {
        #pragma unroll
        for (int it = 0; it < 2; ++it) {
            int f = it * 256 + tid;
            int r = f >> 3, q0 = f & 7;
            int q = q0 ^ (r & 7);
            int node = srcS[SHAPE == 2 ? (kk >> 8) : 0][r];
            int col = (kk & 255) + q * 8;
            gload_lds16(xb + (size_t)node * D + col, xs + f * 16);
        }
        bf16x8 bfr[2][4];
        #pragma unroll
        for (int ks = 0; ks < 2; ++ks)
            #pragma unroll
            for (int nn = 0; nn < 4; ++nn) {
                int j = w * 64 + nn * 16 + l15;
                int k = kk + ks * 32 + l4 * 8;
                bfr[ks][nn] = *(const bf16x8*)(Bt + (size_t)j * K + k);
            }
        __syncthreads();
        #pragma unroll
        for (int ks = 0; ks < 2; ++ks)
            #pragma unroll
            for (int m = 0; m < 4; ++m) {
                int R = m * 16 + l15;
                int C = ks * 4 + l4;
                bf16x8 a = *(const bf16x8*)(xs + R * 128 + ((C ^ (R & 7)) << 4));
                #pragma unroll
                for (int nn = 0; nn < 4; ++nn)
                    acc[m][nn] = __builtin_amdgcn_mfma_f32_16x16x32_bf16(
                        a, bfr[ks][nn], acc[m][nn], 0, 0, 0);
            }
        __syncthreads();
    }
    // epilogue: normalized atomic scatter (dst-sorted -> L2-local)
    #pragma unroll
    for (int m = 0; m < 4; ++m)
        #pragma unroll
        for (int r = 0; r < 4; ++r) {
            int rr = m * 16 + l4 * 4 + r;
            if (rr < nE) {
                float nm = normS[rr];
                size_t ob = (size_t)dstS[rr] * D;
                #pragma unroll
                for (int nn = 0; nn < 4; ++nn) {
                    int col = w * 64 + nn * 16 + l15;
                    atomicAdd(&out[ob + col], nm * acc[m][nn][r]);
                }
            }
        }
}

// ---------------- launch ----------------

extern "C" void kernel_launch(void* const* d_in, const int* in_sizes, int n_in,
                              void* d_out, int out_size, void* d_ws, size_t ws_size,
                              hipStream_t stream) {
    const float* x  = (const float*)d_in[0];
    const int* idx1 = (const int*)d_in[1];
    const int* ty1  = (const int*)d_in[2];
    const int* idx2 = (const int*)d_in[3];
    const int* ty2  = (const int*)d_in[4];
    const float* A1 = (const float*)d_in[5];
    const float* A2 = (const float*)d_in[6];
    const float* W  = (const float*)d_in[7];
    const float* b  = (const float*)d_in[8];
    float* out = (float*)d_out;

    int E1 = in_sizes[2];
    int E2 = in_sizes[4];
    int maxE = E1 > E2 ? E1 : E2;
    const int NCELL = NT * N_NODES;
    const int NB = (NCELL + 1023) / 1024;

    char* p = (char*)d_ws;
    unsigned short* xb  = (unsigned short*)p; p += (size_t)N_NODES * D * 2;   // 51.2 MB
    unsigned short* Wb  = (unsigned short*)p; p += (size_t)D * D * 2;         // 128 KB
    unsigned short* A1T = (unsigned short*)p; p += (size_t)NT * D * 256 * 2;  // 512 KB
    unsigned short* A2T = (unsigned short*)p; p += (size_t)NT * D * 512 * 2;  // 1 MB
    int* counts  = (int*)p; p += (size_t)NCELL * 4;                           // 1.6 MB
    int* cellofs = (int*)p; p += (size_t)NCELL * 4;                           // 1.6 MB
    int* cellcur = (int*)p; p += (size_t)NCELL * 4;                           // 1.6 MB
    int* bsums   = (int*)p; p += 512 * 4;
    int* bucket  = (int*)p; p += (size_t)maxE * 4;                            // 1.2 MB

    // ---- prep: bf16 conversions / transposes ----
    k_cvt<<<(N_NODES * D / 8 + 255) / 256, 256, 0, stream>>>(x, xb, N_NODES * D / 8);
    k_cvt<<<(D * D / 8 + 255) / 256, 256, 0, stream>>>(W, Wb, D * D / 8);
    k_cvt_At<<<dim3(256 / 32, D / 32, NT), dim3(32, 8), 0, stream>>>(A1, A1T, 256);
    k_cvt_At<<<dim3(512 / 32, D / 32, NT), dim3(32, 8), 0, stream>>>(A2, A2T, 512);

    // ---- dense part ----
    k_init_mfma<<<(N_NODES + 63) / 64, 256, 0, stream>>>(xb, Wb, b, out, N_NODES);

    // ---- stage 1 (shape=1): count -> scan -> place((t,dst)-sorted) -> edge GEMM ----
    hipMemsetAsync(counts, 0, (size_t)NCELL * sizeof(int), stream);
    k_count<1><<<(E1 + 255) / 256, 256, 0, stream>>>(idx1, ty1, E1, counts);
    k_scan1<<<NB, 256, 0, stream>>>(counts, NCELL, cellofs, bsums);
    k_scan2<<<1, 512, 0, stream>>>(bsums, NB);
    k_scan3<<<NB, 256, 0, stream>>>(cellofs, cellcur, bsums, NCELL);
    k_place<1><<<(E1 + 255) / 256, 256, 0, stream>>>(idx1, ty1, E1, cellcur, bucket);
    k_edge_mfma<1><<<dim3((E1 + 63) / 64, NT), 256, 0, stream>>>(
        xb, idx1, A1T, out, E1, counts, cellofs, bucket);

    // ---- stage 2 (shape=2) ----
    hipMemsetAsync(counts, 0, (size_t)NCELL * sizeof(int), stream);
    k_count<2><<<(E2 + 255) / 256, 256, 0, stream>>>(idx2, ty2, E2, counts);
    k_scan1<<<NB, 256, 0, stream>>>(counts, NCELL, cellofs, bsums);
    k_scan2<<<1, 512, 0, stream>>>(bsums, NB);
    k_scan3<<<NB, 256, 0, stream>>>(cellofs, cellcur, bsums, NCELL);
    k_place<2><<<(E2 + 255) / 256, 256, 0, stream>>>(idx2, ty2, E2, cellcur, bucket);
    k_edge_mfma<2><<<dim3((E2 + 63) / 64, NT), 256, 0, stream>>>(
        xb, idx2, A2T, out, E2, counts, cellofs, bucket);
}